// Round 7
// baseline (184.960 us; speedup 1.0000x reference)
//
#include <hip/hip_runtime.h>
#include <math.h>

#define N_NODES 50000
#define N_EDGES 1600000
#define D_IN 128
#define D_OUT 32
#define ALPHA 0.2f

#define NB  512      // buckets
#define RPB 98       // rows per bucket (512*98 = 50176 >= 50000)
#define CAP 4096     // slots per bucket (mean 3125, sigma ~56 -> 17 sigma)
#define PT  8        // edges per thread in k_part
#define PB  512      // threads per block in k_part
#define EB  (PT * PB) // 4096 edges per block -> 391 blocks

// Monotone float<->int key (involution). Works with signed atomicMin/Max.
__device__ __forceinline__ int enc_f(float x) {
    int i = __float_as_int(x);
    return i >= 0 ? i : (i ^ 0x7fffffff);
}
__device__ __forceinline__ float dec_f(int k) {
    return __int_as_float(k >= 0 ? k : (k ^ 0x7fffffff));
}

// Kernel A: X_prime = X @ W  [N,32], s0 = Xp.a0, s1 = Xp.a1.
// 8 nodes per 256-thread block; 32 lanes per node (one per output dim).
// Block 0 also zeroes the bucket counters + minmax slots (stream-ordered).
__global__ __launch_bounds__(256) void k_xw(const float* __restrict__ X,
                                            const float* __restrict__ W,
                                            const float* __restrict__ a0,
                                            const float* __restrict__ a1,
                                            float* __restrict__ Xp,
                                            float* __restrict__ s0,
                                            float* __restrict__ s1,
                                            int* __restrict__ minmax,
                                            int* __restrict__ gcount) {
    __shared__ float Wl[D_IN * D_OUT]; // 16 KiB
    __shared__ float Xl[8 * D_IN];     // 4 KiB
    const int tid = threadIdx.x;
    if (blockIdx.x == 0) {
        if (tid == 0) {
            minmax[0] = 0x7fffffff; // running min key
            minmax[1] = 0x80000000; // running max key
        }
        for (int i = tid; i < NB; i += 256) gcount[i] = 0;
    }
    // float4 staging
    const int node0 = blockIdx.x * 8; // 50000/8 = 6250 blocks, no tail
    {
        const float4* W4 = (const float4*)W;
        float4* Wl4 = (float4*)Wl;
#pragma unroll
        for (int i = 0; i < 4; ++i) Wl4[tid + 256 * i] = W4[tid + 256 * i];
        const float4* X4 = (const float4*)(X + (size_t)node0 * D_IN);
        ((float4*)Xl)[tid] = X4[tid];
    }
    __syncthreads();

    const int g = tid >> 5;   // node group within block
    const int t = tid & 31;   // output dim
    const int node = node0 + g;
    const float* xr = &Xl[g * D_IN];
    float acc = 0.f;
#pragma unroll
    for (int k = 0; k < D_IN; ++k) acc += xr[k] * Wl[k * D_OUT + t];
    Xp[(size_t)node * D_OUT + t] = acc;

    float v0 = acc * a0[t];
    float v1 = acc * a1[t];
#pragma unroll
    for (int m = 16; m >= 1; m >>= 1) {
        v0 += __shfl_xor(v0, m);
        v1 += __shfl_xor(v1, m);
    }
    if (t == 0) { s0[node] = v0; s1[node] = v1; }
}

// Kernel B: bucket-partition edges + global min/max.
// Per block: LDS histogram over NB buckets -> one global atomicAdd per
// bucket reserves a contiguous range in that bucket's fixed region ->
// 8B entries {lr<<16|col, leaky_score} written in ~64B per-block bursts.
__global__ __launch_bounds__(PB) void k_part(const int* __restrict__ row,
                                             const int* __restrict__ col,
                                             const float* __restrict__ s0,
                                             const float* __restrict__ s1,
                                             int* __restrict__ gcount,
                                             int* __restrict__ minmax,
                                             uint2* __restrict__ gEdges) {
    __shared__ int hist[NB]; // 2 KB
    __shared__ int lcur[NB]; // 2 KB
    __shared__ int smn[PB / 64], smx[PB / 64];
    const int t = threadIdx.x;
    for (int i = t; i < NB; i += PB) hist[i] = 0;
    __syncthreads();

    const int base = blockIdx.x * EB;
    unsigned px[PT]; // (b:9 | lr:7 | col:16)
    float    fa[PT]; // leaky-relu'd score
    int cnt = 0;
    int kmin = 0x7fffffff, kmax = 0x80000000;
#pragma unroll
    for (int i = 0; i < PT; ++i) {
        const int e = base + i * PB + t;
        if (e >= N_EDGES) break; // e increases with i
        const int r = row[e];
        const int c = col[e];
        float a = s0[r] + s1[c];
        a = a > 0.f ? a : ALPHA * a;
        const int k = enc_f(a);
        kmin = min(kmin, k);
        kmax = max(kmax, k);
        const unsigned b = (unsigned)r / RPB;
        const unsigned lr = (unsigned)r - b * RPB;
        px[cnt] = (b << 23) | (lr << 16) | (unsigned)c;
        fa[cnt] = a;
        ++cnt;
        atomicAdd(&hist[b], 1);
    }
    __syncthreads();
    for (int i = t; i < NB; i += PB) {
        const int h = hist[i];
        lcur[i] = h > 0 ? atomicAdd(&gcount[i], h) : 0;
    }
    __syncthreads();
    for (int j = 0; j < cnt; ++j) {
        const unsigned p = px[j];
        const unsigned b = p >> 23;
        const int pos = atomicAdd(&lcur[b], 1);
        gEdges[(size_t)b * CAP + pos] =
            make_uint2(p & 0x7FFFFFu, (unsigned)__float_as_int(fa[j]));
    }
    // block min/max reduction -> 2 global atomics
#pragma unroll
    for (int m = 32; m >= 1; m >>= 1) {
        kmin = min(kmin, __shfl_xor(kmin, m));
        kmax = max(kmax, __shfl_xor(kmax, m));
    }
    const int wave = t >> 6;
    if ((t & 63) == 0) { smn[wave] = kmin; smx[wave] = kmax; }
    __syncthreads();
    if (t == 0) {
#pragma unroll
        for (int w = 1; w < PB / 64; ++w) {
            kmin = min(kmin, smn[w]);
            kmax = max(kmax, smx[w]);
        }
        atomicMin(&minmax[0], kmin);
        atomicMax(&minmax[1], kmax);
    }
}

// Kernel C: one 512-thread block per bucket (512 blocks, 2 blocks/CU = 50%
// occupancy). ATOMIC-FREE accumulation:
// pass 1: LDS histogram of the bucket's ~3125 edges by local row (98 bins);
// pass 2: counting-sort scatter into LDS {col, exp(minmaxnorm(score))};
// rows:   16 row-processors x 32 lanes walk each row's contiguous segment,
//         accumulating in registers (2-way unrolled independent chains),
//         one coalesced 128B Xp gather per edge; out = acc/wsum directly.
__global__ __launch_bounds__(512) void k_bucket(const int* __restrict__ gcount,
                                                const uint2* __restrict__ gEdges,
                                                const float* __restrict__ Xp,
                                                const int* __restrict__ minmax,
                                                float* __restrict__ out) {
    __shared__ int off[RPB + 1];
    __shared__ int cur[RPB];
    __shared__ int   scol[CAP];  // sorted col (16 KB)
    __shared__ float swt[CAP];   // sorted weight (16 KB)
    const int b = blockIdx.x;
    const int t = threadIdx.x;
    const float mn = dec_f(minmax[0]);
    const float mx = dec_f(minmax[1]);
    const float inv = 1.0f / (mx - mn);
    const int cnt = min(gcount[b], CAP);
    const uint2* eb = gEdges + (size_t)b * CAP;

    // pass 1: histogram (cur used as temp hist)
    if (t < RPB) cur[t] = 0;
    __syncthreads();
    for (int i = t; i < cnt; i += 512) atomicAdd(&cur[eb[i].x >> 16], 1);
    __syncthreads();
    if (t == 0) {
        int run = 0;
#pragma unroll
        for (int r = 0; r < RPB; ++r) { off[r] = run; run += cur[r]; }
        off[RPB] = run;
    }
    __syncthreads();
    if (t < RPB) cur[t] = off[t];
    __syncthreads();
    // pass 2: counting-sort scatter (exp computed once per edge)
    for (int i = t; i < cnt; i += 512) {
        const uint2 e = eb[i];
        const int lr = e.x >> 16;
        const int p = atomicAdd(&cur[lr], 1);
        scol[p] = e.x & 0xFFFF;
        swt[p] = __expf((__int_as_float(e.y) - mn) * inv);
    }
    __syncthreads();

    // row processing: 16 processors x 32 lanes, register accumulation
    const int proc = t >> 5;  // 0..15
    const int d = t & 31;     // output dim
    for (int lr = proc; lr < RPB; lr += 16) {
        const int s = off[lr];
        const int e2 = off[lr + 1];
        float acc0 = 0.f, acc1 = 0.f, ws0 = 0.f, ws1 = 0.f;
        int i = s;
        for (; i + 1 < e2; i += 2) {
            const int c0 = scol[i];
            const int c1 = scol[i + 1];
            const float w0 = swt[i];
            const float w1 = swt[i + 1];
            acc0 += w0 * Xp[(size_t)c0 * D_OUT + d];
            acc1 += w1 * Xp[(size_t)c1 * D_OUT + d];
            ws0 += w0;
            ws1 += w1;
        }
        if (i < e2) {
            const float w0 = swt[i];
            acc0 += w0 * Xp[(size_t)scol[i] * D_OUT + d];
            ws0 += w0;
        }
        const int r = b * RPB + lr;
        if (r < N_NODES)
            out[(size_t)r * D_OUT + d] = (acc0 + acc1) / (ws0 + ws1);
    }
}

extern "C" void kernel_launch(void* const* d_in, const int* in_sizes, int n_in,
                              void* d_out, int out_size, void* d_ws, size_t ws_size,
                              hipStream_t stream) {
    const float* X  = (const float*)d_in[0];
    const float* W  = (const float*)d_in[1];
    const float* a0 = (const float*)d_in[2];
    const float* a1 = (const float*)d_in[3];
    const int* row  = (const int*)d_in[4];
    const int* col  = (const int*)d_in[5];
    float* out = (float*)d_out;

    // Workspace layout (4B units):
    // [minmax: 64][gcount: 2048][s0: 50048][s1: 50048][Xp: 1.6M][gEdges: NB*CAP uint2]
    float* ws = (float*)d_ws;
    int*   minmax = (int*)ws;
    int*   gcount = (int*)(ws + 64);
    float* s0 = ws + 64 + 2048;
    float* s1 = s0 + 50048;
    float* Xp = s1 + 50048;  // 16B-aligned offset
    uint2* gEdges = (uint2*)(Xp + (size_t)N_NODES * D_OUT);

    k_xw<<<N_NODES / 8, 256, 0, stream>>>(X, W, a0, a1, Xp, s0, s1, minmax, gcount);
    k_part<<<(N_EDGES + EB - 1) / EB, PB, 0, stream>>>(row, col, s0, s1, gcount,
                                                       minmax, gEdges);
    k_bucket<<<NB, 512, 0, stream>>>(gcount, gEdges, Xp, minmax, out);
}

// Round 8
// 155.877 us; speedup vs baseline: 1.1866x; 1.1866x over previous
//
#include <hip/hip_runtime.h>
#include <math.h>

#define N_NODES 50000
#define N_EDGES 1600000
#define D_IN 128
#define D_OUT 32
#define ALPHA 0.2f

#define NB  512      // buckets
#define RPB 98       // rows per bucket (512*98 = 50176 >= 50000)
#define HRPB 49      // rows per half-bucket
#define CAP 4096     // slots per bucket (mean ~3136, sigma ~56 -> 17 sigma)
#define CAPH 2048    // staged slots per half-bucket (mean ~1568, 12 sigma)
#define PT  8        // edges per thread in k_part
#define PB  512      // threads per block in k_part
#define EB  (PT * PB) // 4096 edges per block -> 391 blocks
#define XNPB 32      // nodes per block in k_xw

// Monotone float<->int key (involution). Works with signed atomicMin/Max.
__device__ __forceinline__ int enc_f(float x) {
    int i = __float_as_int(x);
    return i >= 0 ? i : (i ^ 0x7fffffff);
}
__device__ __forceinline__ float dec_f(int k) {
    return __int_as_float(k >= 0 ? k : (k ^ 0x7fffffff));
}

// Kernel A: X_prime = X @ W  [N,32], s0 = Xp.a0, s1 = Xp.a1.
// 32 nodes per 256-thread block; 8 lanes per node, 4 dims per lane.
// All LDS traffic is ds_read_b128 (float4): per 4 k-steps, 1 X read + 4 W
// reads per wave. Block 0 also zeroes bucket counters + minmax slots.
__global__ __launch_bounds__(256) void k_xw(const float* __restrict__ X,
                                            const float* __restrict__ W,
                                            const float* __restrict__ a0,
                                            const float* __restrict__ a1,
                                            float* __restrict__ Xp,
                                            float* __restrict__ s0,
                                            float* __restrict__ s1,
                                            int* __restrict__ minmax,
                                            int* __restrict__ gcount) {
    __shared__ float4 Wl4[D_IN * D_OUT / 4]; // 1024 float4 = 16 KB; Wl4[k*8+l] = W[k][4l..4l+4)
    __shared__ float4 Xl4[XNPB * D_IN / 4];  // 1024 float4 = 16 KB; Xl4[g*32+kk]
    const int tid = threadIdx.x;
    if (blockIdx.x == 0) {
        if (tid == 0) {
            minmax[0] = 0x7fffffff; // running min key
            minmax[1] = 0x80000000; // running max key
        }
        for (int i = tid; i < NB; i += 256) gcount[i] = 0;
    }
    const int node0 = blockIdx.x * XNPB;
    {
        const float4* W4 = (const float4*)W;
#pragma unroll
        for (int i = 0; i < 4; ++i) Wl4[tid + 256 * i] = W4[tid + 256 * i];
        const float4* X4 = (const float4*)X + (size_t)node0 * (D_IN / 4);
        const int lim = (min(XNPB, N_NODES - node0)) * (D_IN / 4);
#pragma unroll
        for (int i = 0; i < 4; ++i) {
            const int idx = tid + 256 * i;
            Xl4[idx] = (idx < lim) ? X4[idx] : make_float4(0.f, 0.f, 0.f, 0.f);
        }
    }
    __syncthreads();

    const int g = tid >> 3;  // node within block (0..31)
    const int l = tid & 7;   // lane -> dims [4l, 4l+4)
    const int node = node0 + g;
    const float4* xr = &Xl4[g * (D_IN / 4)];
    float ax = 0.f, ay = 0.f, az = 0.f, aw = 0.f;
#pragma unroll 4
    for (int kk = 0; kk < D_IN / 4; ++kk) {
        const float4 xv = xr[kk];
        const float4 w0 = Wl4[(4 * kk + 0) * 8 + l];
        const float4 w1 = Wl4[(4 * kk + 1) * 8 + l];
        const float4 w2 = Wl4[(4 * kk + 2) * 8 + l];
        const float4 w3 = Wl4[(4 * kk + 3) * 8 + l];
        ax += xv.x * w0.x + xv.y * w1.x + xv.z * w2.x + xv.w * w3.x;
        ay += xv.x * w0.y + xv.y * w1.y + xv.z * w2.y + xv.w * w3.y;
        az += xv.x * w0.z + xv.y * w1.z + xv.z * w2.z + xv.w * w3.z;
        aw += xv.x * w0.w + xv.y * w1.w + xv.z * w2.w + xv.w * w3.w;
    }
    if (node < N_NODES)
        ((float4*)Xp)[(size_t)node * 8 + l] = make_float4(ax, ay, az, aw);

    const float4 A0 = ((const float4*)a0)[l];
    const float4 A1 = ((const float4*)a1)[l];
    float v0 = ax * A0.x + ay * A0.y + az * A0.z + aw * A0.w;
    float v1 = ax * A1.x + ay * A1.y + az * A1.z + aw * A1.w;
#pragma unroll
    for (int m = 4; m >= 1; m >>= 1) {
        v0 += __shfl_xor(v0, m);
        v1 += __shfl_xor(v1, m);
    }
    if (l == 0 && node < N_NODES) { s0[node] = v0; s1[node] = v1; }
}

// Kernel B: bucket-partition edges + global min/max.
// Per block: LDS histogram over NB buckets -> one global atomicAdd per
// bucket reserves a contiguous range in that bucket's fixed region ->
// 8B entries {lr<<16|col, leaky_score} written in ~64B per-block bursts.
__global__ __launch_bounds__(PB) void k_part(const int* __restrict__ row,
                                             const int* __restrict__ col,
                                             const float* __restrict__ s0,
                                             const float* __restrict__ s1,
                                             int* __restrict__ gcount,
                                             int* __restrict__ minmax,
                                             uint2* __restrict__ gEdges) {
    __shared__ int hist[NB]; // 2 KB
    __shared__ int lcur[NB]; // 2 KB
    __shared__ int smn[PB / 64], smx[PB / 64];
    const int t = threadIdx.x;
    for (int i = t; i < NB; i += PB) hist[i] = 0;
    __syncthreads();

    const int base = blockIdx.x * EB;
    unsigned px[PT]; // (b:9 | lr:7 | col:16)
    float    fa[PT]; // leaky-relu'd score
    int cnt = 0;
    int kmin = 0x7fffffff, kmax = 0x80000000;
#pragma unroll
    for (int i = 0; i < PT; ++i) {
        const int e = base + i * PB + t;
        if (e >= N_EDGES) break; // e increases with i
        const int r = row[e];
        const int c = col[e];
        float a = s0[r] + s1[c];
        a = a > 0.f ? a : ALPHA * a;
        const int k = enc_f(a);
        kmin = min(kmin, k);
        kmax = max(kmax, k);
        const unsigned b = (unsigned)r / RPB;
        const unsigned lr = (unsigned)r - b * RPB;
        px[cnt] = (b << 23) | (lr << 16) | (unsigned)c;
        fa[cnt] = a;
        ++cnt;
        atomicAdd(&hist[b], 1);
    }
    __syncthreads();
    for (int i = t; i < NB; i += PB) {
        const int h = hist[i];
        lcur[i] = h > 0 ? atomicAdd(&gcount[i], h) : 0;
    }
    __syncthreads();
    for (int j = 0; j < cnt; ++j) {
        const unsigned p = px[j];
        const unsigned b = p >> 23;
        const int pos = atomicAdd(&lcur[b], 1);
        gEdges[(size_t)b * CAP + pos] =
            make_uint2(p & 0x7FFFFFu, (unsigned)__float_as_int(fa[j]));
    }
    // block min/max reduction -> 2 global atomics
#pragma unroll
    for (int m = 32; m >= 1; m >>= 1) {
        kmin = min(kmin, __shfl_xor(kmin, m));
        kmax = max(kmax, __shfl_xor(kmax, m));
    }
    const int wave = t >> 6;
    if ((t & 63) == 0) { smn[wave] = kmin; smx[wave] = kmax; }
    __syncthreads();
    if (t == 0) {
#pragma unroll
        for (int w = 1; w < PB / 64; ++w) {
            kmin = min(kmin, smn[w]);
            kmax = max(kmax, smx[w]);
        }
        atomicMin(&minmax[0], kmin);
        atomicMax(&minmax[1], kmax);
    }
}

// Kernel C: one 512-thread block per HALF-bucket (1024 blocks, ~12.5 KB LDS
// -> 4 blocks/CU = full wave occupancy). ATOMIC-FREE accumulation:
// pass 1: LDS histogram of this half's rows (49 bins) over the bucket list;
// pass 2: counting-sort scatter into LDS {col:u16, exp(minmaxnorm(score))};
// rows:   16 row-processors x 32 lanes walk each row's contiguous segment,
//         4-way unrolled independent register accumulators, one coalesced
//         128B Xp gather per edge; out = acc/wsum written directly.
__global__ __launch_bounds__(512, 8) void k_bucket(const int* __restrict__ gcount,
                                                   const uint2* __restrict__ gEdges,
                                                   const float* __restrict__ Xp,
                                                   const int* __restrict__ minmax,
                                                   float* __restrict__ out) {
    __shared__ unsigned short scol[CAPH]; // 4 KB
    __shared__ float swt[CAPH];           // 8 KB
    __shared__ int off[HRPB + 1];
    __shared__ int cur[HRPB];
    const int bid = blockIdx.x;
    const int b = bid >> 1;
    const int lo = (bid & 1) * HRPB;
    const int t = threadIdx.x;
    const float mn = dec_f(minmax[0]);
    const float mx = dec_f(minmax[1]);
    const float inv = 1.0f / (mx - mn);
    const int cnt = min(gcount[b], CAP);
    const uint2* eb = gEdges + (size_t)b * CAP;

    // pass 1: histogram of this half's rows (cur as temp hist)
    if (t < HRPB) cur[t] = 0;
    __syncthreads();
    for (int i = t; i < cnt; i += 512) {
        const int lrl = (int)(eb[i].x >> 16) - lo;
        if ((unsigned)lrl < (unsigned)HRPB) atomicAdd(&cur[lrl], 1);
    }
    __syncthreads();
    if (t == 0) {
        int run = 0;
#pragma unroll
        for (int r = 0; r < HRPB; ++r) { off[r] = run; run += cur[r]; }
        off[HRPB] = run;
    }
    __syncthreads();
    if (t < HRPB) cur[t] = off[t];
    __syncthreads();
    // pass 2: counting-sort scatter (exp computed once per edge)
    for (int i = t; i < cnt; i += 512) {
        const uint2 e = eb[i];
        const int lrl = (int)(e.x >> 16) - lo;
        if ((unsigned)lrl < (unsigned)HRPB) {
            const int p = atomicAdd(&cur[lrl], 1);
            scol[p] = (unsigned short)(e.x & 0xFFFFu);
            swt[p] = __expf((__int_as_float(e.y) - mn) * inv);
        }
    }
    __syncthreads();

    // row processing: 16 processors x 32 lanes, 4-way unrolled reg accumulation
    const int proc = t >> 5;  // 0..15
    const int d = t & 31;     // output dim
    for (int lrl = proc; lrl < HRPB; lrl += 16) {
        const int s = off[lrl];
        const int e2 = off[lrl + 1];
        float ac0 = 0.f, ac1 = 0.f, ac2 = 0.f, ac3 = 0.f;
        float w0s = 0.f, w1s = 0.f, w2s = 0.f, w3s = 0.f;
        int i = s;
        for (; i + 3 < e2; i += 4) {
            const int c0 = scol[i];
            const int c1 = scol[i + 1];
            const int c2 = scol[i + 2];
            const int c3 = scol[i + 3];
            const float w0 = swt[i];
            const float w1 = swt[i + 1];
            const float w2 = swt[i + 2];
            const float w3 = swt[i + 3];
            ac0 += w0 * Xp[(size_t)c0 * D_OUT + d];
            ac1 += w1 * Xp[(size_t)c1 * D_OUT + d];
            ac2 += w2 * Xp[(size_t)c2 * D_OUT + d];
            ac3 += w3 * Xp[(size_t)c3 * D_OUT + d];
            w0s += w0; w1s += w1; w2s += w2; w3s += w3;
        }
        for (; i < e2; ++i) {
            const float w0 = swt[i];
            ac0 += w0 * Xp[(size_t)scol[i] * D_OUT + d];
            w0s += w0;
        }
        const int r = b * RPB + lo + lrl;
        if (r < N_NODES)
            out[(size_t)r * D_OUT + d] =
                (ac0 + ac1 + ac2 + ac3) / (w0s + w1s + w2s + w3s);
    }
}

extern "C" void kernel_launch(void* const* d_in, const int* in_sizes, int n_in,
                              void* d_out, int out_size, void* d_ws, size_t ws_size,
                              hipStream_t stream) {
    const float* X  = (const float*)d_in[0];
    const float* W  = (const float*)d_in[1];
    const float* a0 = (const float*)d_in[2];
    const float* a1 = (const float*)d_in[3];
    const int* row  = (const int*)d_in[4];
    const int* col  = (const int*)d_in[5];
    float* out = (float*)d_out;

    // Workspace layout (4B units):
    // [minmax: 64][gcount: 2048][s0: 50048][s1: 50048][Xp: 1.6M][gEdges: NB*CAP uint2]
    float* ws = (float*)d_ws;
    int*   minmax = (int*)ws;
    int*   gcount = (int*)(ws + 64);
    float* s0 = ws + 64 + 2048;
    float* s1 = s0 + 50048;
    float* Xp = s1 + 50048;  // 16B-aligned offset
    uint2* gEdges = (uint2*)(Xp + (size_t)N_NODES * D_OUT);

    k_xw<<<(N_NODES + XNPB - 1) / XNPB, 256, 0, stream>>>(X, W, a0, a1, Xp, s0, s1,
                                                          minmax, gcount);
    k_part<<<(N_EDGES + EB - 1) / EB, PB, 0, stream>>>(row, col, s0, s1, gcount,
                                                       minmax, gEdges);
    k_bucket<<<NB * 2, 512, 0, stream>>>(gcount, gEdges, Xp, minmax, out);
}